// Round 6
// baseline (139.889 us; speedup 1.0000x reference)
//
#include <hip/hip_runtime.h>
#include <hip/hip_bf16.h>

using u32 = unsigned int;
using u16 = unsigned short;

typedef __attribute__((ext_vector_type(8))) _Float16 half8;
typedef __attribute__((ext_vector_type(2))) _Float16 half2v;
typedef __attribute__((ext_vector_type(16))) float f32x16;
typedef __attribute__((ext_vector_type(4))) u32 u32x4;

#define IN_K   4096
#define OUT_N  14336
#define SPLITK 8
#define NSTAGE 4                 // 4 stages x 128k = 512k per block
#define OUT_ELEMS (64 * OUT_N)   // 917504

// ---------------------------------------------------------------------------
// prep: x f32[64][4096] -> xs f16 in MFMA-fragment order.
// xs layout: [512 chunks][64 rows][8 f16]; chunk c covers k = 8c + perm[j],
// perm = {0,4,1,5,2,6,3,7} (matches pair-dequant element order).
__global__ __launch_bounds__(256) void prep_kernel(const float* __restrict__ x,
                                                   u16* __restrict__ xs) {
  const int t = blockIdx.x * 256 + threadIdx.x;   // 32768 threads
  const int c = t >> 6;        // chunk 0..511
  const int r = t & 63;        // row
  const float* px = x + r * IN_K + c * 8;
  const float4 a = *(const float4*)px;
  const float4 b = *(const float4*)(px + 4);
  const float af[4] = {a.x, a.y, a.z, a.w};
  const float bf[4] = {b.x, b.y, b.z, b.w};
  union { u32x4 v; u32 u[4]; } o;
#pragma unroll
  for (int i = 0; i < 4; ++i) {
    const _Float16 hl = (_Float16)af[i];   // k = 8c + i
    const _Float16 hh = (_Float16)bf[i];   // k = 8c + i + 4
    u16 lo, hi;
    __builtin_memcpy(&lo, &hl, 2);
    __builtin_memcpy(&hi, &hh, 2);
    o.u[i] = (u32)lo | ((u32)hi << 16);
  }
  *(u32x4*)(xs + (size_t)t * 8) = o.v;
}

// ---------------------------------------------------------------------------
__global__ __launch_bounds__(256) void bias_init_kernel(const float* __restrict__ bias,
                                                        float* __restrict__ out) {
  const int i = (blockIdx.x * 256 + threadIdx.x) * 4;
  const int col = i % OUT_N;
  *(float4*)(out + i) = *(const float4*)(bias + col);
}

// ---------------------------------------------------------------------------
// qgemm: grid (112, 8), 4 waves/block. Wave = 32 cols x 64 rows x 512 k.
// A staged to LDS via global_load_lds (double-buffered, counted vmcnt),
// qweight/scale/zero prefetched via a depth-3 ring, dequant in-register f16.
// FUSED: split-K partials + per-bx semaphore; the 8th finisher reduces all 8
// partials (L2-hot) + bias -> out. Deterministic (fixed by-order sum).
template <bool FUSED>
__global__ __launch_bounds__(256, 3) void qgemm_kernel(
    const u32* __restrict__ qw, const u32* __restrict__ qz,
    const float* __restrict__ scal, const u16* __restrict__ xs,
    const float* __restrict__ bias, float* __restrict__ part,
    int* __restrict__ cnt, float* __restrict__ out) {
  __shared__ u16 lds[2][8192];             // 2 x 16 KB stages
  __shared__ int red_flag;
  const int tid = threadIdx.x;
  const int lane = tid & 63;
  const int wv = tid >> 6;
  const int g = lane >> 5;                 // k-half within 16k step
  const int nn = lane & 31;
  const int bx = blockIdx.x;
  const int by = blockIdx.y;
  const int colabs = bx * 128 + wv * 32 + nn;
  const int chunk0 = by * 64;              // global 8k-chunk base (== qw row base)
  const int grp0 = by * NSTAGE;            // quant groups handled by this block
  const int zsh = (colabs & 7) * 4;

  f32x16 acc0, acc1;
#pragma unroll
  for (int i = 0; i < 16; ++i) { acc0[i] = 0.f; acc1[i] = 0.f; }

  // A-tile stage: 16 KB contiguous, 4 x 16B per thread  (4 VMEM)
  auto issue = [&](int st) {
    const u16* src = xs + (size_t)(chunk0 + st * 16) * 512;
    u16* dstl = &lds[st & 1][0];
#pragma unroll
    for (int r = 0; r < 4; ++r) {
      const int p = r * 256 + tid;
      __builtin_amdgcn_global_load_lds(
          (const __attribute__((address_space(1))) void*)(src + p * 8),
          (__attribute__((address_space(3))) void*)(dstl + p * 8), 16, 0, 0);
    }
  };
  // qweight + scale + zero for one stage (== one group): exactly 10 VMEM
  auto loadQ = [&](int st, u32* qr, float& sr, u32& zr) {
    const int c = chunk0 + st * 16;
#pragma unroll
    for (int s = 0; s < 8; ++s)
      qr[s] = qw[(size_t)(c + 2 * s + g) * OUT_N + colabs];
    sr = scal[(size_t)(grp0 + st) * OUT_N + colabs];
    zr = qz[(size_t)(grp0 + st) * (OUT_N / 8) + (colabs >> 3)];
  };

  u32 qb[3][8]; float sb[3]; u32 zb[3];
  issue(0);                              // A0: 4 VMEM
  loadQ(0, qb[0], sb[0], zb[0]);         // Q0: 10
  loadQ(1, qb[1], sb[1], zb[1]);         // Q1: 10  -> 24 outstanding

  // wait schedule (in-order vmcnt retirement):
  // st0: +A1 -> 28, wait(24) retires A0; then +Q2
  // st1: +A2 -> 28, wait(14) retires Q1,A1; then +Q3
  // st2: +A3 -> 28, wait(14) retires Q2,A2
  // st3: wait(0)
#pragma unroll
  for (int st = 0; st < NSTAGE; ++st) {
    if (st == 0) {
      issue(1);
      asm volatile("s_waitcnt vmcnt(24)" ::: "memory");
    } else if (st < NSTAGE - 1) {
      __builtin_amdgcn_s_barrier();                 // WAR on buf[(st+1)&1]
      issue(st + 1);
      asm volatile("s_waitcnt vmcnt(14)" ::: "memory");
    } else {
      __builtin_amdgcn_s_barrier();
      asm volatile("s_waitcnt vmcnt(0)" ::: "memory");
    }
    __builtin_amdgcn_s_barrier();                   // stage st LDS visible
    asm volatile("" ::: "memory");

    if (st < NSTAGE - 2)
      loadQ(st + 2, qb[(st + 2) % 3], sb[(st + 2) % 3], zb[(st + 2) % 3]);

    const u32* qc = qb[st % 3];
    const float scur = sb[st % 3];
    const u32 zcur = zb[st % 3];

    // dequant constants for this group (GROUP = 128 k = 1 stage)
    const u32 zq = (zcur >> zsh) & 0xFu;
    const u32 hzu = 0x64016401u + zq * 0x00010001u;   // f16x2 of (1025+z)
    half2v hz; __builtin_memcpy(&hz, &hzu, 4);
    const _Float16 hs = (_Float16)scur;
    const half2v s2 = {hs, hs};

    const u16* buf = &lds[st & 1][0];
    __builtin_amdgcn_s_setprio(1);
#pragma unroll
    for (int s = 0; s < 8; ++s) {
      const int cl = s * 2 + g;
      const half8 a0 = *(const half8*)(buf + (cl * 64 + nn) * 8);
      const half8 a1 = *(const half8*)(buf + (cl * 64 + nn + 32) * 8);
      const u32 q = qc[s];
      const u32 p0 = (q & 0x000F000Fu) | 0x64006400u;          // (n0,n4)+1024
      const u32 p1 = ((q >> 4) & 0x000F000Fu) | 0x64006400u;   // (n1,n5)+1024
      const u32 p2 = ((q >> 8) & 0x000F000Fu) | 0x64006400u;   // (n2,n6)+1024
      const u32 p3 = ((q >> 12) & 0x000F000Fu) | 0x64006400u;  // (n3,n7)+1024
      half2v t0, t1, t2, t3;
      __builtin_memcpy(&t0, &p0, 4);
      __builtin_memcpy(&t1, &p1, 4);
      __builtin_memcpy(&t2, &p2, 4);
      __builtin_memcpy(&t3, &p3, 4);
      union { half8 v; half2v h[4]; } bb;
      bb.h[0] = (t0 - hz) * s2;    // exact int sub, then scale (v_pk_*_f16)
      bb.h[1] = (t1 - hz) * s2;
      bb.h[2] = (t2 - hz) * s2;
      bb.h[3] = (t3 - hz) * s2;
      acc0 = __builtin_amdgcn_mfma_f32_32x32x16_f16(a0, bb.v, acc0, 0, 0, 0);
      acc1 = __builtin_amdgcn_mfma_f32_32x32x16_f16(a1, bb.v, acc1, 0, 0, 0);
    }
    __builtin_amdgcn_s_setprio(0);
  }

  // C/D layout: col = lane&31, row = (r&3) + 8*(r>>2) + 4*(lane>>5)
  if (!FUSED) {
#pragma unroll
    for (int r = 0; r < 16; ++r) {
      const int row = (r & 3) + 8 * (r >> 2) + 4 * g;
      unsafeAtomicAdd(&out[(size_t)row * OUT_N + colabs], acc0[r]);
      unsafeAtomicAdd(&out[(size_t)(row + 32) * OUT_N + colabs], acc1[r]);
    }
    return;
  }

  // ---- fused split-K epilogue ----
  // partials tiled [bx][by][64][128], 32 KB contiguous per block
  {
    float* p = part + ((size_t)bx * SPLITK + by) * 8192 + wv * 32 + nn;
#pragma unroll
    for (int r = 0; r < 16; ++r) {
      const int row = (r & 3) + 8 * (r >> 2) + 4 * g;
      p[(size_t)row * 128] = acc0[r];
      p[(size_t)(row + 32) * 128] = acc1[r];
    }
  }
  __threadfence();                         // release: partial visible device-wide
  __builtin_amdgcn_s_barrier();            // all waves of block fenced
  if (tid == 0)
    red_flag = (atomicAdd(&cnt[bx], 1) == SPLITK - 1);
  __syncthreads();                         // broadcast red_flag
  if (red_flag) {
    __threadfence();                       // acquire: discard stale cached lines
    const float* pb = part + (size_t)bx * SPLITK * 8192;
#pragma unroll
    for (int k = 0; k < 8; ++k) {
      const int pos = (k * 256 + tid) * 4; // 0..8188, step 4
      const int col = pos & 127;
      const int row = pos >> 7;
      float4 r = *(const float4*)(bias + bx * 128 + col);
#pragma unroll
      for (int b = 0; b < SPLITK; ++b) {
        const float4 a = *(const float4*)(pb + (size_t)b * 8192 + pos);
        r.x += a.x; r.y += a.y; r.z += a.z; r.w += a.w;
      }
      *(float4*)(out + (size_t)row * OUT_N + bx * 128 + col) = r;
    }
  }
}

// ---------------------------------------------------------------------------
extern "C" void kernel_launch(void* const* d_in, const int* in_sizes, int n_in,
                              void* d_out, int out_size, void* d_ws, size_t ws_size,
                              hipStream_t stream) {
  (void)in_sizes; (void)n_in; (void)out_size;
  const float* x    = (const float*)d_in[0];
  const u32*   qw   = (const u32*)d_in[1];
  const u32*   qz   = (const u32*)d_in[2];
  const float* sc   = (const float*)d_in[3];
  const float* bias = (const float*)d_in[4];
  // d_in[5] = g_idx: sequential k/128 for this problem; folded into indexing.
  float* out = (float*)d_out;

  const size_t XS_BYTES   = (size_t)64 * IN_K * 2;                    // 512 KB
  const size_t PART_BYTES = (size_t)SPLITK * 112 * 8192 * 4;          // 29.36 MB
  const size_t CNT_BYTES  = 112 * sizeof(int);
  u16* xs = (u16*)d_ws;

  prep_kernel<<<128, 256, 0, stream>>>(x, xs);

  if (ws_size >= XS_BYTES + PART_BYTES + CNT_BYTES) {
    float* part = (float*)((char*)d_ws + XS_BYTES);
    int*   cnt  = (int*)((char*)d_ws + XS_BYTES + PART_BYTES);
    hipMemsetAsync(cnt, 0, CNT_BYTES, stream);
    qgemm_kernel<true><<<dim3(112, SPLITK), 256, 0, stream>>>(
        qw, qz, sc, xs, bias, part, cnt, out);
  } else {
    bias_init_kernel<<<896, 256, 0, stream>>>(bias, out);
    qgemm_kernel<false><<<dim3(112, SPLITK), 256, 0, stream>>>(
        qw, qz, sc, xs, bias, nullptr, nullptr, out);
  }
}

// Round 7
// 28.778 us; speedup vs baseline: 4.8611x; 4.8611x over previous
//
#include <hip/hip_runtime.h>
#include <hip/hip_bf16.h>

using u32 = unsigned int;
using u16 = unsigned short;

typedef __attribute__((ext_vector_type(8))) _Float16 half8;
typedef __attribute__((ext_vector_type(2))) _Float16 half2v;
typedef __attribute__((ext_vector_type(16))) float f32x16;
typedef __attribute__((ext_vector_type(4))) u32 u32x4;

#define IN_K   4096
#define OUT_N  14336
#define SPLITK 4
#define NSTAGE 8                 // 8 stages x 128k = 1024k per block
#define OUT_ELEMS (64 * OUT_N)   // 917504

// ---------------------------------------------------------------------------
// prep: x f32[64][4096] -> xs f16 in MFMA-fragment order.
// xs layout: [512 chunks][64 rows][8 f16]; chunk c covers k = 8c + perm[j],
// perm = {0,4,1,5,2,6,3,7} (matches pair-dequant element order).
__global__ __launch_bounds__(256) void prep_kernel(const float* __restrict__ x,
                                                   u16* __restrict__ xs) {
  const int t = blockIdx.x * 256 + threadIdx.x;   // 32768 threads
  const int c = t >> 6;        // chunk 0..511
  const int r = t & 63;        // row
  const float* px = x + r * IN_K + c * 8;
  const float4 a = *(const float4*)px;
  const float4 b = *(const float4*)(px + 4);
  const float af[4] = {a.x, a.y, a.z, a.w};
  const float bf[4] = {b.x, b.y, b.z, b.w};
  union { u32x4 v; u32 u[4]; } o;
#pragma unroll
  for (int i = 0; i < 4; ++i) {
    const _Float16 hl = (_Float16)af[i];   // k = 8c + i
    const _Float16 hh = (_Float16)bf[i];   // k = 8c + i + 4
    u16 lo, hi;
    __builtin_memcpy(&lo, &hl, 2);
    __builtin_memcpy(&hi, &hh, 2);
    o.u[i] = (u32)lo | ((u32)hi << 16);
  }
  *(u32x4*)(xs + (size_t)t * 8) = o.v;
}

// ---------------------------------------------------------------------------
__global__ __launch_bounds__(256) void bias_init_kernel(const float* __restrict__ bias,
                                                        float* __restrict__ out) {
  const int i = (blockIdx.x * 256 + threadIdx.x) * 4;
  const int col = i % OUT_N;
  *(float4*)(out + i) = *(const float4*)(bias + col);
}

// reduce: grid (112, 8). Block (bx, ry): cols bx*128..+128, rows ry*8..+8.
// Partials tiled [bx][by][64][128].
__global__ __launch_bounds__(256) void reduce_kernel(const float* __restrict__ part,
                                                     const float* __restrict__ bias,
                                                     float* __restrict__ out) {
  const int bx = blockIdx.x, ry = blockIdx.y, t = threadIdx.x;
  const int row = ry * 8 + (t >> 5);
  const int c4 = (t & 31) * 4;
  const float* p = part + (((size_t)bx * SPLITK) * 64 + row) * 128 + c4;
  float4 r = *(const float4*)(bias + bx * 128 + c4);
#pragma unroll
  for (int by = 0; by < SPLITK; ++by) {
    const float4 a = *(const float4*)(p + (size_t)by * 64 * 128);
    r.x += a.x; r.y += a.y; r.z += a.z; r.w += a.w;
  }
  *(float4*)(out + (size_t)row * OUT_N + bx * 128 + c4) = r;
}

// ---------------------------------------------------------------------------
// qgemm: grid (112, 4), 4 waves/block. Wave = 32 cols x 64 rows x 1024 k.
// BOTH A and qweight staged to LDS via global_load_lds width-16 (few, large
// requests instead of 10 scalar-dword miss streams per wave-stage).
// Scales/zeros for all 8 groups preloaded to registers. Double-buffered,
// counted vmcnt(6) ring, R2 barrier discipline.
template <bool ATOMIC>
__global__ __launch_bounds__(256, 2) void qgemm_kernel(
    const u32* __restrict__ qw, const u32* __restrict__ qz,
    const float* __restrict__ scal, const u16* __restrict__ xs,
    float* __restrict__ dst) {
  __shared__ u16 alds[2][8192];            // 2 x 16 KB A stages
  __shared__ u32 qlds[2][2048];            // 2 x 8 KB  Q stages (16 rows x 128 cols)
  const int tid = threadIdx.x;
  const int lane = tid & 63;
  const int wv = tid >> 6;
  const int g = lane >> 5;                 // k-half within 16k step
  const int nn = lane & 31;
  const int bx = blockIdx.x;
  const int by = blockIdx.y;
  const int colabs = bx * 128 + wv * 32 + nn;
  const int chunk0 = by * 128;             // qw row base / xs chunk base
  const int grp0 = by * NSTAGE;            // 8 quant groups per block
  const int zsh = (colabs & 7) * 4;

  f32x16 acc0, acc1;
#pragma unroll
  for (int i = 0; i < 16; ++i) { acc0[i] = 0.f; acc1[i] = 0.f; }

  // ---- scales & zero-words for all 8 groups -> registers (16 VMEM) ----
  float sv[NSTAGE]; u32 zv[NSTAGE];
#pragma unroll
  for (int t = 0; t < NSTAGE; ++t) {
    sv[t] = scal[(size_t)(grp0 + t) * OUT_N + colabs];
    zv[t] = qz[(size_t)(grp0 + t) * (OUT_N / 8) + (colabs >> 3)];
  }

  // ---- stage issue: A (4 instr/thread) + Q (2 instr/thread) = 6/wave ----
  auto issue = [&](int st) {
    const u16* asrc = xs + (size_t)(chunk0 + st * 16) * 512;   // 16 KB linear
    u16* adst = &alds[st & 1][0];
#pragma unroll
    for (int r = 0; r < 4; ++r) {
      const int p = r * 256 + tid;
      __builtin_amdgcn_global_load_lds(
          (const __attribute__((address_space(1))) void*)(asrc + p * 8),
          (__attribute__((address_space(3))) void*)(adst + p * 8), 16, 0, 0);
    }
    // Q tile: rows chunk0+st*16+j (j=0..15), cols bx*128..+128 (512 B/row)
    u32* qdst = &qlds[st & 1][0];
#pragma unroll
    for (int r = 0; r < 2; ++r) {
      const int p = r * 256 + tid;           // 0..511 16B-chunks
      const int j = p >> 5;                  // row 0..15
      const int cg = p & 31;                 // 16B col-group
      const u32* src = qw + (size_t)(chunk0 + st * 16 + j) * OUT_N
                          + bx * 128 + cg * 4;
      __builtin_amdgcn_global_load_lds(
          (const __attribute__((address_space(1))) void*)src,
          (__attribute__((address_space(3))) void*)(qdst + p * 4), 16, 0, 0);
    }
  };

  issue(0);   // 6 outstanding (+16 sz already in flight)

#pragma unroll
  for (int st = 0; st < NSTAGE; ++st) {
    if (st == 0) {
      issue(1);                                        // +6
      // retire sz(16) + AQ(0)(6); leave AQ(1)=6 in flight
      asm volatile("s_waitcnt vmcnt(6)" ::: "memory");
    } else if (st < NSTAGE - 1) {
      __builtin_amdgcn_s_barrier();                    // WAR on buf[(st+1)&1]
      issue(st + 1);                                   // +6 -> 12
      asm volatile("s_waitcnt vmcnt(6)" ::: "memory"); // AQ(st) complete
    } else {
      __builtin_amdgcn_s_barrier();
      asm volatile("s_waitcnt vmcnt(0)" ::: "memory");
    }
    __builtin_amdgcn_s_barrier();                      // stage st visible
    asm volatile("" ::: "memory");

    // dequant constants for this group (GROUP = 128 k = 1 stage)
    const u32 zq = (zv[st] >> zsh) & 0xFu;
    const u32 hzu = 0x64016401u + zq * 0x00010001u;    // f16x2 of (1025+z)
    half2v hz; __builtin_memcpy(&hz, &hzu, 4);
    const _Float16 hs = (_Float16)sv[st];
    const half2v s2 = {hs, hs};

    const u16* abuf = &alds[st & 1][0];
    const u32* qbuf = &qlds[st & 1][0];
#pragma unroll
    for (int s = 0; s < 8; ++s) {
      const int cl = s * 2 + g;
      const half8 a0 = *(const half8*)(abuf + (cl * 64 + nn) * 8);
      const half8 a1 = *(const half8*)(abuf + (cl * 64 + nn + 32) * 8);
      const u32 q = qbuf[cl * 128 + wv * 32 + nn];
      const u32 p0 = (q & 0x000F000Fu) | 0x64006400u;          // (n0,n4)+1024
      const u32 p1 = ((q >> 4) & 0x000F000Fu) | 0x64006400u;   // (n1,n5)+1024
      const u32 p2 = ((q >> 8) & 0x000F000Fu) | 0x64006400u;   // (n2,n6)+1024
      const u32 p3 = ((q >> 12) & 0x000F000Fu) | 0x64006400u;  // (n3,n7)+1024
      half2v t0, t1, t2, t3;
      __builtin_memcpy(&t0, &p0, 4);
      __builtin_memcpy(&t1, &p1, 4);
      __builtin_memcpy(&t2, &p2, 4);
      __builtin_memcpy(&t3, &p3, 4);
      union { half8 v; half2v h[4]; } bb;
      bb.h[0] = (t0 - hz) * s2;    // exact int sub, then scale (v_pk_*_f16)
      bb.h[1] = (t1 - hz) * s2;
      bb.h[2] = (t2 - hz) * s2;
      bb.h[3] = (t3 - hz) * s2;
      acc0 = __builtin_amdgcn_mfma_f32_32x32x16_f16(a0, bb.v, acc0, 0, 0, 0);
      acc1 = __builtin_amdgcn_mfma_f32_32x32x16_f16(a1, bb.v, acc1, 0, 0, 0);
    }
  }

  // C/D layout: col = lane&31, row = (r&3) + 8*(r>>2) + 4*(lane>>5)
#pragma unroll
  for (int r = 0; r < 16; ++r) {
    const int row = (r & 3) + 8 * (r >> 2) + 4 * g;
    if (ATOMIC) {
      unsafeAtomicAdd(&dst[(size_t)row * OUT_N + colabs], acc0[r]);
      unsafeAtomicAdd(&dst[(size_t)(row + 32) * OUT_N + colabs], acc1[r]);
    } else {
      // tiled partials: [bx][by][64][128], 32 KB contiguous per block
      float* p = dst + (((size_t)bx * SPLITK + by) * 64) * 128 + wv * 32 + nn;
      p[(size_t)row * 128] = acc0[r];
      p[(size_t)(row + 32) * 128] = acc1[r];
    }
  }
}

// ---------------------------------------------------------------------------
extern "C" void kernel_launch(void* const* d_in, const int* in_sizes, int n_in,
                              void* d_out, int out_size, void* d_ws, size_t ws_size,
                              hipStream_t stream) {
  (void)in_sizes; (void)n_in; (void)out_size;
  const float* x    = (const float*)d_in[0];
  const u32*   qw   = (const u32*)d_in[1];
  const u32*   qz   = (const u32*)d_in[2];
  const float* sc   = (const float*)d_in[3];
  const float* bias = (const float*)d_in[4];
  // d_in[5] = g_idx: sequential k/128 for this problem; folded into indexing.
  float* out = (float*)d_out;

  const size_t XS_BYTES   = (size_t)64 * IN_K * 2;                 // 512 KB
  const size_t PART_BYTES = (size_t)SPLITK * 112 * 8192 * 4;       // 14.68 MB
  u16* xs = (u16*)d_ws;

  prep_kernel<<<128, 256, 0, stream>>>(x, xs);

  if (ws_size >= XS_BYTES + PART_BYTES) {
    float* part = (float*)((char*)d_ws + XS_BYTES);
    qgemm_kernel<false><<<dim3(112, SPLITK), 256, 0, stream>>>(qw, qz, sc, xs, part);
    reduce_kernel<<<dim3(112, 8), 256, 0, stream>>>(part, bias, out);
  } else {
    bias_init_kernel<<<896, 256, 0, stream>>>(bias, out);
    qgemm_kernel<true><<<dim3(112, SPLITK), 256, 0, stream>>>(qw, qz, sc, xs, out);
  }
}